// Round 9
// baseline (2739.595 us; speedup 1.0000x reference)
//
#include <hip/hip_runtime.h>
#include <hip/hip_bf16.h>
#include <stdint.h>
#include <stddef.h>

typedef unsigned short ushort_t;
typedef __attribute__((ext_vector_type(8))) short short8;
typedef __attribute__((ext_vector_type(4))) short short4_t;
typedef __attribute__((ext_vector_type(4))) float f32x4;
typedef __attribute__((ext_vector_type(2))) unsigned int uint2_t;

#define TT 1024
#define BB 128
#define NG 400   // 4*H
#define HID 100

#define ALIGN256(x) ((((size_t)(x)) + 255) & ~(size_t)255)

// ---------------- ws layout (bytes) ----------------
static const size_t WS_FLAG = 0;                                  // int: 1=bf16 inputs, 0=fp32
static const size_t WS_XT   = 4096;                               // (1024,128,128) bf16
static const size_t WS_OUT0 = WS_XT   + (size_t)1024 * 128 * 128 * 2;  // (1024,128,256) bf16
static const size_t WS_GX   = WS_OUT0 + (size_t)1024 * 128 * 256 * 2;  // (2,1024,8,6400) bf16 permuted
static const size_t WS_WIH0 = WS_GX   + (size_t)2 * 1024 * 128 * 400 * 2; // (2,400,128) bf16
static const size_t WS_WHH  = WS_WIH0 + (size_t)2 * 400 * 128 * 2;        // (2,2,400,128) bf16
static const size_t WS_WIH1 = WS_WHH  + (size_t)2 * 2 * 400 * 128 * 2;    // (2,400,256) bf16
static const size_t WS_BIAS = WS_WIH1 + (size_t)2 * 400 * 256 * 2;        // (2,2,400) f32

// ---------------- helpers ----------------
__device__ __forceinline__ float bf2f(ushort_t v) {
  return __builtin_bit_cast(float, ((unsigned)v) << 16);
}
__device__ __forceinline__ ushort_t f2bf(float f) {
  unsigned u = __builtin_bit_cast(unsigned, f);
  u += 0x7FFF + ((u >> 16) & 1);   // RNE
  return (ushort_t)(u >> 16);
}
// flag-based load: bf16 passthrough or fp32->bf16
__device__ __forceinline__ ushort_t ldbf(const void* p, size_t i, int isbf) {
  return isbf ? ((const ushort_t*)p)[i] : f2bf(((const float*)p)[i]);
}
__device__ __forceinline__ float ldf(const void* p, size_t i, int isbf) {
  return isbf ? bf2f(((const ushort_t*)p)[i]) : ((const float*)p)[i];
}
__device__ __forceinline__ float fexp2(float x) {
#if __has_builtin(__builtin_amdgcn_exp2f)
  return __builtin_amdgcn_exp2f(x);
#else
  return __exp2f(x);
#endif
}
__device__ __forceinline__ float frcp(float x) {
#if __has_builtin(__builtin_amdgcn_rcpf)
  return __builtin_amdgcn_rcpf(x);
#else
  return 1.0f / x;
#endif
}
__device__ __forceinline__ float sigm(float x) {
  return frcp(1.0f + fexp2(-1.44269504f * x));
}
__device__ __forceinline__ float tanh_(float x) {
  return 1.0f - 2.0f * frcp(1.0f + fexp2(2.88539008f * x));
}

// ---------------- input dtype detection ----------------
__global__ __launch_bounds__(256) void detect_dtype(const ushort_t* __restrict__ x,
                                                    int* __restrict__ flag) {
  __shared__ int cnt;
  if (threadIdx.x == 0) cnt = 0;
  __syncthreads();
  int local = 0;
  for (int i = threadIdx.x; i < 4096; i += 256) {
    ushort_t u = x[2 * i];
    int e = (u >> 7) & 0xFF;
    if (e >= 0x66 && e <= 0x85) local++;
  }
  atomicAdd(&cnt, local);
  __syncthreads();
  if (threadIdx.x == 0) *flag = (cnt >= 2048) ? 1 : 0;
}

// ---------------- weight prep (reads raw fp32-or-bf16 via flag) ----------------
// Gate permutation: np = 4*j + g  <->  n = g*100 + j  (torch order i,f,g,o)
__global__ __launch_bounds__(256) void prep_weights(
    const void* __restrict__ wih0, const void* __restrict__ whh0,
    const void* __restrict__ b0,   const void* __restrict__ wih1,
    const void* __restrict__ whh1, const void* __restrict__ b1,
    ushort_t* __restrict__ WIH0, ushort_t* __restrict__ WHH,
    ushort_t* __restrict__ WIH1, float* __restrict__ BIAS,
    const int* __restrict__ flag)
{
  const int isbf = *flag;
  int tid = blockIdx.x * blockDim.x + threadIdx.x;
  int nth = gridDim.x * blockDim.x;
  for (int idx = tid; idx < 2 * NG * 128; idx += nth) {          // WIH0 [d][np][k]
    int k = idx & 127; int np = (idx >> 7) % NG; int d = idx / (NG * 128);
    int n = (np & 3) * HID + (np >> 2);
    WIH0[idx] = (k < HID) ? ldbf(wih0, (size_t)(d * NG + n) * 100 + k, isbf) : (ushort_t)0;
  }
  for (int idx = tid; idx < 2 * 2 * NG * 128; idx += nth) {      // WHH [l][d][np][k]
    int k = idx & 127; int np = (idx >> 7) % NG; int dl = idx / (NG * 128);
    int d = dl & 1; int l = dl >> 1;
    int n = (np & 3) * HID + (np >> 2);
    const void* src = l ? whh1 : whh0;
    WHH[idx] = (k < HID) ? ldbf(src, (size_t)(d * NG + n) * 100 + k, isbf) : (ushort_t)0;
  }
  for (int idx = tid; idx < 2 * NG * 256; idx += nth) {          // WIH1 [d][np][k]
    int k = idx & 255; int np = (idx >> 8) % NG; int d = idx / (NG * 256);
    int n = (np & 3) * HID + (np >> 2);
    int c = (k < 100) ? k : ((k >= 128 && k < 228) ? (k - 28) : -1);
    WIH1[idx] = (c >= 0) ? ldbf(wih1, (size_t)(d * NG + n) * 200 + c, isbf) : (ushort_t)0;
  }
  for (int idx = tid; idx < 2 * 2 * NG; idx += nth) {            // BIAS [l][d][np] f32
    int np = idx % NG; int dl = idx / NG; int d = dl & 1; int l = dl >> 1;
    int n = (np & 3) * HID + (np >> 2);
    BIAS[idx] = ldf(l ? b1 : b0, d * NG + n, isbf);
  }
}

// ---------------- pack x: (B,100,T) raw -> xT (T,B,128) bf16 zero-padded ----------------
__global__ __launch_bounds__(256) void pack_x(const void* __restrict__ x,
                                              ushort_t* __restrict__ xT,
                                              const int* __restrict__ flag)
{
  __shared__ ushort_t tile[100][68];
  const int isbf = *flag;
  const int b = blockIdx.x;
  const int t0 = blockIdx.y << 6;
  for (int i = threadIdx.x; i < 100 * 64; i += 256) {
    int k = i >> 6, t = i & 63;
    tile[k][t] = ldbf(x, ((size_t)b * 100 + k) * TT + t0 + t, isbf);
  }
  __syncthreads();
  for (int i = threadIdx.x; i < 128 * 64; i += 256) {
    int k = i & 127, t = i >> 7;
    xT[((size_t)(t0 + t) * BB + b) * 128 + k] = (k < 100) ? tile[k][t] : (ushort_t)0;
  }
}

// ---------------- zero out0 pad columns (cols 100..127 and 228..255) ----------------
// out0 is uninitialized workspace; gemm_gx(layer1) multiplies those columns by zero
// weights, but garbage bf16 could be Inf/NaN and 0*NaN = NaN. Zero them once.
__global__ __launch_bounds__(256) void zero_out0_pads(unsigned* __restrict__ o) {
  int tid = blockIdx.x * blockDim.x + threadIdx.x;   // 1024*128*32 threads
  int r = tid >> 5, u = tid & 31;
  if (u < 28) {
    int cu = (u < 14) ? (50 + u) : (100 + u);        // uint cols 50..63, 114..127
    o[(size_t)r * 128 + cu] = 0u;
  }
}

// ---------------- gx GEMM: writes permuted gx layout ----------------
// gx block for (d,t,bg): 6400 ushorts, inner = (nt*64 + lm_rec*4 + quad_rec)*4 + gamma.
// R8: operand-swapped MFMA (bb, a) -> lane(quad,lm) reg r holds np=nt*16+quad*4+r,
// batch m=lm; the 4 gates of one gx item are contiguous -> one 8B packed store.
// R9: the gemm is LATENCY-bound, not issue-bound (R7 K-loop neutral, R8 epilogue
// near-neutral; ~1.7 TB/s effective vs 35-45us write floor). M=32 per block
// (acc 2x7xf32x4 = 56 VGPR) + __launch_bounds__(256,4) -> VGPR cap 128,
// 16 waves/CU = 4 waves/SIMD = 2x the latency hiding of the M=64/(256,2) form.
// B-reuse drops 4x->2x but W is L2-resident (<=200KB) — extra L2 reads are free.
template<int KPAD>
__global__ __launch_bounds__(256, 4) void gemm_gx(
    const ushort_t* __restrict__ A, const ushort_t* __restrict__ W,
    const float* __restrict__ BIASL, ushort_t* __restrict__ gxo)
{
  constexpr int NKT = KPAD >> 5;
  const int mt0 = blockIdx.x * 2;      // first of 2 m-tiles; rows m = mt*16..mt*16+15
  const int d = blockIdx.y;
  const int w = threadIdx.x >> 6;
  const int lane = threadIdx.x & 63;
  const int quad = lane >> 4;
  const int lm = lane & 15;

  f32x4 acc[2][7];
#pragma unroll
  for (int mt = 0; mt < 2; mt++)
#pragma unroll
    for (int i = 0; i < 7; i++) acc[mt][i] = (f32x4){0.f, 0.f, 0.f, 0.f};

  const ushort_t* Wd = W + (size_t)d * NG * KPAD;
  const ushort_t* Ap = A + (size_t)(mt0 * 16 + lm) * KPAD + quad * 8;

#pragma unroll
  for (int kt = 0; kt < NKT; kt++) {
    short8 a[2];
#pragma unroll
    for (int mt = 0; mt < 2; mt++)
      a[mt] = *(const short8*)(Ap + (size_t)mt * 16 * KPAD + kt * 32);
#pragma unroll
    for (int i = 0; i < 7; i++) {
      int nt = w + 4 * i;
      if (nt < 25) {                                 // wave-uniform
        short8 bb = *(const short8*)(Wd + (size_t)(nt * 16 + lm) * KPAD + kt * 32 + quad * 8);
#pragma unroll
        for (int mt = 0; mt < 2; mt++)
          acc[mt][i] = __builtin_amdgcn_mfma_f32_16x16x32_bf16(bb, a[mt], acc[mt][i], 0, 0, 0);
      }
    }
  }

  const float* bd = BIASL + d * NG;
#pragma unroll
  for (int mt = 0; mt < 2; mt++) {
    const int mtile = mt0 + mt;
    const int t = mtile >> 3, bg = mtile & 7;
    ushort_t* go = gxo + (((size_t)d * TT + t) * 8 + bg) * 6400;
#pragma unroll
    for (int i = 0; i < 7; i++) {
      int nt = w + 4 * i;
      if (nt >= 25) break;                           // wave-uniform
      f32x4 bv = *(const f32x4*)(bd + nt * 16 + quad * 4);   // BIAS[np..np+3]
      unsigned lo = (unsigned)f2bf(acc[mt][i][0] + bv[0]) |
                    ((unsigned)f2bf(acc[mt][i][1] + bv[1]) << 16);
      unsigned hi = (unsigned)f2bf(acc[mt][i][2] + bv[2]) |
                    ((unsigned)f2bf(acc[mt][i][3] + bv[3]) << 16);
      uint2_t u; u.x = lo; u.y = hi;
      *(uint2_t*)(go + (nt * 64 + lm * 4 + quad) * 4) = u;
    }
  }
}

// ---------------- recurrent LSTM layer (FROZEN at R6 form, 1140us/layer) ----------------
// grid: 16 blocks = 2 dirs x 8 row-groups of 16 batch rows; 512 threads = 8 waves.
// STRUCTURE = v0: plain __syncthreads, stores in the epilogue (pre-barrier),
// per-step gx prefetch in its original position. Journal:
// R1 raw-barrier 1425us; R2 2-dirs/block 2387us; R3 store-burst 1558us;
// R5 loop-top delayed stores 1330us — ALL store/sync restructurings regress.
// R6: 7-trans epilogue is duration-NEUTRAL (VALU busy-time -12%, dur same) =>
// the step is bound by the serial phase chain (barrier -> 32 redundant
// ds_read_b128 on the CU LDS pipe -> 4-deep MFMA chains -> trans chain ->
// barrier), not by issue. Per-SIMD trans floor ~700cyc/step is structural
// (items must colocate per (dir,bg) CU for the LDS h-exchange). DO NOT TOUCH.
template<bool F32OUT>
__global__ __launch_bounds__(512, 1) void lstm_layer(
    const ushort_t* __restrict__ gx, const ushort_t* __restrict__ WHHl,
    void* __restrict__ outp, int ostride, int colmult)
{
  const int dir = blockIdx.x >> 3;
  const int bg = blockIdx.x & 7;
  const int b0 = bg << 4;
  const int w = threadIdx.x >> 6;
  const int lane = threadIdx.x & 63;
  const int quad = lane >> 4;
  const int lm = lane & 15;
  const int ocol = dir * colmult;

  __shared__ ushort_t hbuf[2][16][136];   // [buf][batch row][unit k], K padded to 128
  for (int i = threadIdx.x; i < 2 * 16 * 136; i += 512) ((ushort_t*)hbuf)[i] = 0;

  // persistent W_hh A-fragments: A[m=np=nt*16+lm][k=quad*8+j]
  short8 afragW[4][4];
  int nts[4];
#pragma unroll
  for (int i = 0; i < 4; i++) {
    int nt = (i < 3) ? (w + 8 * i) : 24;
    nts[i] = nt;
    const ushort_t* wp = WHHl + ((size_t)dir * NG + nt * 16 + lm) * 128;
#pragma unroll
    for (int kt = 0; kt < 4; kt++)
      afragW[i][kt] = *(const short8*)(wp + kt * 32 + quad * 8);
  }

  // per-tile gx lane offsets (ushorts), constant over t
  int loff[4];
#pragma unroll
  for (int i = 0; i < 4; i++) loff[i] = (nts[i] * 64 + lm * 4 + quad) * 4;

  float cst[4] = {0.f, 0.f, 0.f, 0.f};    // cell state: item (unit nts[i]*4+quad, batch lm)
  const ushort_t* gxd = gx + ((size_t)dir * TT * 8 + bg) * 6400;

  short4_t pf[4];                          // gx prefetch (4 gates of item, 8B each)
  {
    int tt0 = dir ? (TT - 1) : 0;
    const ushort_t* gp = gxd + (size_t)tt0 * 8 * 6400;
#pragma unroll
    for (int i = 0; i < 4; i++) pf[i] = *(const short4_t*)(gp + loff[i]);
  }

  const float K1 = 1.44269504f;            // log2(e)
  const float K2 = 2.88539008f;            // 2*log2(e)

  __syncthreads();

  for (int t = 0; t < TT; t++) {
    const int tt = dir ? (TT - 1 - t) : t;
    const int pb = t & 1;

    // init accumulators from prefetched gx (reg r == gate gamma)
    f32x4 acc[4];
#pragma unroll
    for (int i = 0; i < 4; i++) {
#pragma unroll
      for (int r = 0; r < 4; r++) acc[i][r] = bf2f((ushort_t)pf[i][r]);
    }

    // prefetch next step's gx (overlaps MFMA + epilogue)
    if (t + 1 < TT) {
      int tn = dir ? (TT - 2 - t) : (t + 1);
      const ushort_t* gp = gxd + (size_t)tn * 8 * 6400;
#pragma unroll
      for (int i = 0; i < 4; i++) pf[i] = *(const short4_t*)(gp + loff[i]);
    }

    // B fragments: h, B[n=batch lm][k=quad*8+j]
    short8 bfr[4];
#pragma unroll
    for (int kt = 0; kt < 4; kt++)
      bfr[kt] = *(const short8*)(&hbuf[pb][lm][kt * 32 + quad * 8]);

#pragma unroll
    for (int i = 0; i < 4; i++) {
      if (i == 3 && w != 0) continue;      // wave-uniform
#pragma unroll
      for (int kt = 0; kt < 4; kt++)
        acc[i] = __builtin_amdgcn_mfma_f32_16x16x32_bf16(afragW[i][kt], bfr[kt], acc[i], 0, 0, 0);
    }

    // epilogue: gates are acc[i][0..3] directly; 7 transcendentals per item
#pragma unroll
    for (int i = 0; i < 4; i++) {
      if (i == 3 && w != 0) continue;
      float gi = acc[i][0], gf = acc[i][1], gg = acc[i][2], go = acc[i][3];
      float a  = 1.0f + fexp2(-K1 * gi);   // 1/sigm(gi)
      float b  = 1.0f + fexp2( K2 * gg);   // tanh(gg) = (b-2)/b
      float af = 1.0f + fexp2(-K1 * gf);   // 1/sigm(gf)
      float ab = a * b;
      float num = cst[i] * ab + (b - 2.0f) * af;
      float cn  = num * frcp(af * ab);
      cst[i] = cn;
      float c_ = 1.0f + fexp2(-K1 * go);   // 1/sigm(go)
      float cnc = fminf(cn, 30.0f);        // tanh(30)==1 in fp32; avoids inf/inf
      float d_ = 1.0f + fexp2( K2 * cnc);  // tanh(cn) = (d-2)/d
      float h  = (d_ - 2.0f) * frcp(c_ * d_);
      int j = nts[i] * 4 + quad;           // unit index
      hbuf[pb ^ 1][lm][j] = f2bf(h);
      size_t oidx = ((size_t)tt * BB + b0 + lm) * ostride + ocol + j;
      if (F32OUT) ((float*)outp)[oidx] = h;
      else        ((ushort_t*)outp)[oidx] = f2bf(h);
    }
    __syncthreads();
  }
}

// ---------------- launch ----------------
extern "C" void kernel_launch(void* const* d_in, const int* in_sizes, int n_in,
                              void* d_out, int out_size, void* d_ws, size_t ws_size,
                              hipStream_t stream) {
  const void* x_raw    = d_in[0];
  const void* wih0_raw = d_in[1];
  const void* whh0_raw = d_in[2];
  const void* b0_raw   = d_in[3];
  const void* wih1_raw = d_in[4];
  const void* whh1_raw = d_in[5];
  const void* b1_raw   = d_in[6];

  char* ws = (char*)d_ws;
  int*      FLAG = (int*)(ws + WS_FLAG);
  ushort_t* xT   = (ushort_t*)(ws + WS_XT);
  ushort_t* out0 = (ushort_t*)(ws + WS_OUT0);
  ushort_t* gx   = (ushort_t*)(ws + WS_GX);
  ushort_t* WIH0 = (ushort_t*)(ws + WS_WIH0);
  ushort_t* WHH  = (ushort_t*)(ws + WS_WHH);
  ushort_t* WIH1 = (ushort_t*)(ws + WS_WIH1);
  float*    BIAS = (float*)(ws + WS_BIAS);

  // 1) detect input dtype (data-dependent only -> graph-safe)
  detect_dtype<<<1, 256, 0, stream>>>((const ushort_t*)x_raw, FLAG);

  // 2) prep (flag-based inline conversion, no separate cvt passes)
  prep_weights<<<256, 256, 0, stream>>>(wih0_raw, whh0_raw, b0_raw,
                                        wih1_raw, whh1_raw, b1_raw,
                                        WIH0, WHH, WIH1, BIAS, FLAG);
  pack_x<<<dim3(128, 16), 256, 0, stream>>>(x_raw, xT, FLAG);
  zero_out0_pads<<<16384, 256, 0, stream>>>((unsigned*)out0);

  // layer 0 (bf16 internal output)
  gemm_gx<128><<<dim3(4096, 2), 256, 0, stream>>>(xT, WIH0, BIAS, gx);
  lstm_layer<false><<<16, 512, 0, stream>>>(gx, WHH, out0, 256, 128);
  // layer 1 (fp32 output to d_out)
  gemm_gx<256><<<dim3(4096, 2), 256, 0, stream>>>(out0, WIH1, BIAS + 2 * NG, gx);
  lstm_layer<true><<<16, 512, 0, stream>>>(gx, WHH + (size_t)2 * NG * 128, d_out, 200, 100);
}

// Round 10
// 2600.857 us; speedup vs baseline: 1.0533x; 1.0533x over previous
//
#include <hip/hip_runtime.h>
#include <hip/hip_bf16.h>
#include <stdint.h>
#include <stddef.h>

typedef unsigned short ushort_t;
typedef __attribute__((ext_vector_type(8))) short short8;
typedef __attribute__((ext_vector_type(4))) short short4_t;
typedef __attribute__((ext_vector_type(4))) float f32x4;
typedef __attribute__((ext_vector_type(2))) unsigned int uint2_t;

#define TT 1024
#define BB 128
#define NG 400   // 4*H
#define HID 100

#define ALIGN256(x) ((((size_t)(x)) + 255) & ~(size_t)255)

// ---------------- ws layout (bytes) ----------------
static const size_t WS_FLAG = 0;                                  // int: 1=bf16 inputs, 0=fp32
static const size_t WS_XT   = 4096;                               // (1024,128,128) bf16
static const size_t WS_OUT0 = WS_XT   + (size_t)1024 * 128 * 128 * 2;  // (1024,128,256) bf16
static const size_t WS_GX   = WS_OUT0 + (size_t)1024 * 128 * 256 * 2;  // (2,1024,8,6400) bf16 permuted
static const size_t WS_WIH0 = WS_GX   + (size_t)2 * 1024 * 128 * 400 * 2; // (2,400,128) bf16
static const size_t WS_WHH  = WS_WIH0 + (size_t)2 * 400 * 128 * 2;        // (2,2,400,128) bf16
static const size_t WS_WIH1 = WS_WHH  + (size_t)2 * 2 * 400 * 128 * 2;    // (2,400,256) bf16
static const size_t WS_BIAS = WS_WIH1 + (size_t)2 * 400 * 256 * 2;        // (2,2,400) f32

// ---------------- helpers ----------------
__device__ __forceinline__ float bf2f(ushort_t v) {
  return __builtin_bit_cast(float, ((unsigned)v) << 16);
}
__device__ __forceinline__ ushort_t f2bf(float f) {
  unsigned u = __builtin_bit_cast(unsigned, f);
  u += 0x7FFF + ((u >> 16) & 1);   // RNE
  return (ushort_t)(u >> 16);
}
// flag-based load: bf16 passthrough or fp32->bf16
__device__ __forceinline__ ushort_t ldbf(const void* p, size_t i, int isbf) {
  return isbf ? ((const ushort_t*)p)[i] : f2bf(((const float*)p)[i]);
}
__device__ __forceinline__ float ldf(const void* p, size_t i, int isbf) {
  return isbf ? bf2f(((const ushort_t*)p)[i]) : ((const float*)p)[i];
}
__device__ __forceinline__ float fexp2(float x) {
#if __has_builtin(__builtin_amdgcn_exp2f)
  return __builtin_amdgcn_exp2f(x);
#else
  return __exp2f(x);
#endif
}
__device__ __forceinline__ float frcp(float x) {
#if __has_builtin(__builtin_amdgcn_rcpf)
  return __builtin_amdgcn_rcpf(x);
#else
  return 1.0f / x;
#endif
}
__device__ __forceinline__ float sigm(float x) {
  return frcp(1.0f + fexp2(-1.44269504f * x));
}
__device__ __forceinline__ float tanh_(float x) {
  return 1.0f - 2.0f * frcp(1.0f + fexp2(2.88539008f * x));
}

// ---------------- input dtype detection ----------------
__global__ __launch_bounds__(256) void detect_dtype(const ushort_t* __restrict__ x,
                                                    int* __restrict__ flag) {
  __shared__ int cnt;
  if (threadIdx.x == 0) cnt = 0;
  __syncthreads();
  int local = 0;
  for (int i = threadIdx.x; i < 4096; i += 256) {
    ushort_t u = x[2 * i];
    int e = (u >> 7) & 0xFF;
    if (e >= 0x66 && e <= 0x85) local++;
  }
  atomicAdd(&cnt, local);
  __syncthreads();
  if (threadIdx.x == 0) *flag = (cnt >= 2048) ? 1 : 0;
}

// ---------------- weight prep (reads raw fp32-or-bf16 via flag) ----------------
// Gate permutation: np = 4*j + g  <->  n = g*100 + j  (torch order i,f,g,o)
__global__ __launch_bounds__(256) void prep_weights(
    const void* __restrict__ wih0, const void* __restrict__ whh0,
    const void* __restrict__ b0,   const void* __restrict__ wih1,
    const void* __restrict__ whh1, const void* __restrict__ b1,
    ushort_t* __restrict__ WIH0, ushort_t* __restrict__ WHH,
    ushort_t* __restrict__ WIH1, float* __restrict__ BIAS,
    const int* __restrict__ flag)
{
  const int isbf = *flag;
  int tid = blockIdx.x * blockDim.x + threadIdx.x;
  int nth = gridDim.x * blockDim.x;
  for (int idx = tid; idx < 2 * NG * 128; idx += nth) {          // WIH0 [d][np][k]
    int k = idx & 127; int np = (idx >> 7) % NG; int d = idx / (NG * 128);
    int n = (np & 3) * HID + (np >> 2);
    WIH0[idx] = (k < HID) ? ldbf(wih0, (size_t)(d * NG + n) * 100 + k, isbf) : (ushort_t)0;
  }
  for (int idx = tid; idx < 2 * 2 * NG * 128; idx += nth) {      // WHH [l][d][np][k]
    int k = idx & 127; int np = (idx >> 7) % NG; int dl = idx / (NG * 128);
    int d = dl & 1; int l = dl >> 1;
    int n = (np & 3) * HID + (np >> 2);
    const void* src = l ? whh1 : whh0;
    WHH[idx] = (k < HID) ? ldbf(src, (size_t)(d * NG + n) * 100 + k, isbf) : (ushort_t)0;
  }
  for (int idx = tid; idx < 2 * NG * 256; idx += nth) {          // WIH1 [d][np][k]
    int k = idx & 255; int np = (idx >> 8) % NG; int d = idx / (NG * 256);
    int n = (np & 3) * HID + (np >> 2);
    int c = (k < 100) ? k : ((k >= 128 && k < 228) ? (k - 28) : -1);
    WIH1[idx] = (c >= 0) ? ldbf(wih1, (size_t)(d * NG + n) * 200 + c, isbf) : (ushort_t)0;
  }
  for (int idx = tid; idx < 2 * 2 * NG; idx += nth) {            // BIAS [l][d][np] f32
    int np = idx % NG; int dl = idx / NG; int d = dl & 1; int l = dl >> 1;
    int n = (np & 3) * HID + (np >> 2);
    BIAS[idx] = ldf(l ? b1 : b0, d * NG + n, isbf);
  }
}

// ---------------- pack x: (B,100,T) raw -> xT (T,B,128) bf16 zero-padded ----------------
__global__ __launch_bounds__(256) void pack_x(const void* __restrict__ x,
                                              ushort_t* __restrict__ xT,
                                              const int* __restrict__ flag)
{
  __shared__ ushort_t tile[100][68];
  const int isbf = *flag;
  const int b = blockIdx.x;
  const int t0 = blockIdx.y << 6;
  for (int i = threadIdx.x; i < 100 * 64; i += 256) {
    int k = i >> 6, t = i & 63;
    tile[k][t] = ldbf(x, ((size_t)b * 100 + k) * TT + t0 + t, isbf);
  }
  __syncthreads();
  for (int i = threadIdx.x; i < 128 * 64; i += 256) {
    int k = i & 127, t = i >> 7;
    xT[((size_t)(t0 + t) * BB + b) * 128 + k] = (k < 100) ? tile[k][t] : (ushort_t)0;
  }
}

// ---------------- zero out0 pad columns (cols 100..127 and 228..255) ----------------
// out0 is uninitialized workspace; gemm_gx(layer1) multiplies those columns by zero
// weights, but garbage bf16 could be Inf/NaN and 0*NaN = NaN. Zero them once.
__global__ __launch_bounds__(256) void zero_out0_pads(unsigned* __restrict__ o) {
  int tid = blockIdx.x * blockDim.x + threadIdx.x;   // 1024*128*32 threads
  int r = tid >> 5, u = tid & 31;
  if (u < 28) {
    int cu = (u < 14) ? (50 + u) : (100 + u);        // uint cols 50..63, 114..127
    o[(size_t)r * 128 + cu] = 0u;
  }
}

// ---------------- gx GEMM: writes permuted gx layout ----------------
// gx block for (d,t,bg): 6400 ushorts, inner = (nt*64 + lm_rec*4 + quad_rec)*4 + gamma.
// R8 body (best measured: 2661us total): M=64 per block (4 m-tiles, 4x B-reuse),
// operand-swapped MFMA (bb, a) -> lane(quad,lm) reg r holds np=nt*16+quad*4+r,
// batch m=lm; the 4 gates of one gx item are contiguous -> one 8B packed store.
// Journal: R7 K-loop unroll neutral; R8 epilogue pack ~neutral; R9 M=32/(256,4)
// REGRESSED (-78us): reuse beats occupancy for this shape.
// R10 tweaks (structure unchanged):
//  (a) __launch_bounds__(256,3): same M=64 reuse, VGPR cap 168 (est. live ~160)
//      -> 3 waves/SIMD, +50% latency hiding at CONSTANT reuse.
//  (b) 1-D grid, d = bid&1: the d=0/d=1 blocks reading the SAME 64 A-rows are
//      dispatch-adjacent (were ~2048 apart in the (N,2) grid) -> A re-read L2-hits.
template<int KPAD>
__global__ __launch_bounds__(256, 3) void gemm_gx(
    const ushort_t* __restrict__ A, const ushort_t* __restrict__ W,
    const float* __restrict__ BIASL, ushort_t* __restrict__ gxo)
{
  constexpr int NKT = KPAD >> 5;
  const int d = blockIdx.x & 1;
  const int mt0 = (blockIdx.x >> 1) * 4;   // first of 4 m-tiles
  const int w = threadIdx.x >> 6;
  const int lane = threadIdx.x & 63;
  const int quad = lane >> 4;
  const int lm = lane & 15;

  f32x4 acc[4][7];
#pragma unroll
  for (int mt = 0; mt < 4; mt++)
#pragma unroll
    for (int i = 0; i < 7; i++) acc[mt][i] = (f32x4){0.f, 0.f, 0.f, 0.f};

  const ushort_t* Wd = W + (size_t)d * NG * KPAD;
  const ushort_t* Ap = A + (size_t)(mt0 * 16 + lm) * KPAD + quad * 8;

#pragma unroll
  for (int kt = 0; kt < NKT; kt++) {
    short8 a[4];
#pragma unroll
    for (int mt = 0; mt < 4; mt++)
      a[mt] = *(const short8*)(Ap + (size_t)mt * 16 * KPAD + kt * 32);
#pragma unroll
    for (int i = 0; i < 7; i++) {
      int nt = w + 4 * i;
      if (nt < 25) {                                 // wave-uniform
        short8 bb = *(const short8*)(Wd + (size_t)(nt * 16 + lm) * KPAD + kt * 32 + quad * 8);
#pragma unroll
        for (int mt = 0; mt < 4; mt++)
          acc[mt][i] = __builtin_amdgcn_mfma_f32_16x16x32_bf16(bb, a[mt], acc[mt][i], 0, 0, 0);
      }
    }
  }

  const float* bd = BIASL + d * NG;
#pragma unroll
  for (int mt = 0; mt < 4; mt++) {
    const int mtile = mt0 + mt;
    const int t = mtile >> 3, bg = mtile & 7;
    ushort_t* go = gxo + (((size_t)d * TT + t) * 8 + bg) * 6400;
#pragma unroll
    for (int i = 0; i < 7; i++) {
      int nt = w + 4 * i;
      if (nt >= 25) break;                           // wave-uniform
      f32x4 bv = *(const f32x4*)(bd + nt * 16 + quad * 4);   // BIAS[np..np+3]
      unsigned lo = (unsigned)f2bf(acc[mt][i][0] + bv[0]) |
                    ((unsigned)f2bf(acc[mt][i][1] + bv[1]) << 16);
      unsigned hi = (unsigned)f2bf(acc[mt][i][2] + bv[2]) |
                    ((unsigned)f2bf(acc[mt][i][3] + bv[3]) << 16);
      uint2_t u; u.x = lo; u.y = hi;
      *(uint2_t*)(go + (nt * 64 + lm * 4 + quad) * 4) = u;
    }
  }
}

// ---------------- recurrent LSTM layer (FROZEN at R6 form, 1140us/layer) ----------------
// grid: 16 blocks = 2 dirs x 8 row-groups of 16 batch rows; 512 threads = 8 waves.
// STRUCTURE = v0: plain __syncthreads, stores in the epilogue (pre-barrier),
// per-step gx prefetch in its original position. Journal:
// R1 raw-barrier 1425us; R2 2-dirs/block 2387us; R3 store-burst 1558us;
// R5 loop-top delayed stores 1330us — ALL store/sync restructurings regress.
// R6: 7-trans epilogue is duration-NEUTRAL (VALU busy-time -12%, dur same) =>
// the step is bound by the serial phase chain (barrier -> 32 redundant
// ds_read_b128 on the CU LDS pipe -> 4-deep MFMA chains -> trans chain ->
// barrier), not by issue. Per-SIMD trans floor ~700cyc/step is structural
// (items must colocate per (dir,bg) CU for the LDS h-exchange). DO NOT TOUCH.
template<bool F32OUT>
__global__ __launch_bounds__(512, 1) void lstm_layer(
    const ushort_t* __restrict__ gx, const ushort_t* __restrict__ WHHl,
    void* __restrict__ outp, int ostride, int colmult)
{
  const int dir = blockIdx.x >> 3;
  const int bg = blockIdx.x & 7;
  const int b0 = bg << 4;
  const int w = threadIdx.x >> 6;
  const int lane = threadIdx.x & 63;
  const int quad = lane >> 4;
  const int lm = lane & 15;
  const int ocol = dir * colmult;

  __shared__ ushort_t hbuf[2][16][136];   // [buf][batch row][unit k], K padded to 128
  for (int i = threadIdx.x; i < 2 * 16 * 136; i += 512) ((ushort_t*)hbuf)[i] = 0;

  // persistent W_hh A-fragments: A[m=np=nt*16+lm][k=quad*8+j]
  short8 afragW[4][4];
  int nts[4];
#pragma unroll
  for (int i = 0; i < 4; i++) {
    int nt = (i < 3) ? (w + 8 * i) : 24;
    nts[i] = nt;
    const ushort_t* wp = WHHl + ((size_t)dir * NG + nt * 16 + lm) * 128;
#pragma unroll
    for (int kt = 0; kt < 4; kt++)
      afragW[i][kt] = *(const short8*)(wp + kt * 32 + quad * 8);
  }

  // per-tile gx lane offsets (ushorts), constant over t
  int loff[4];
#pragma unroll
  for (int i = 0; i < 4; i++) loff[i] = (nts[i] * 64 + lm * 4 + quad) * 4;

  float cst[4] = {0.f, 0.f, 0.f, 0.f};    // cell state: item (unit nts[i]*4+quad, batch lm)
  const ushort_t* gxd = gx + ((size_t)dir * TT * 8 + bg) * 6400;

  short4_t pf[4];                          // gx prefetch (4 gates of item, 8B each)
  {
    int tt0 = dir ? (TT - 1) : 0;
    const ushort_t* gp = gxd + (size_t)tt0 * 8 * 6400;
#pragma unroll
    for (int i = 0; i < 4; i++) pf[i] = *(const short4_t*)(gp + loff[i]);
  }

  const float K1 = 1.44269504f;            // log2(e)
  const float K2 = 2.88539008f;            // 2*log2(e)

  __syncthreads();

  for (int t = 0; t < TT; t++) {
    const int tt = dir ? (TT - 1 - t) : t;
    const int pb = t & 1;

    // init accumulators from prefetched gx (reg r == gate gamma)
    f32x4 acc[4];
#pragma unroll
    for (int i = 0; i < 4; i++) {
#pragma unroll
      for (int r = 0; r < 4; r++) acc[i][r] = bf2f((ushort_t)pf[i][r]);
    }

    // prefetch next step's gx (overlaps MFMA + epilogue)
    if (t + 1 < TT) {
      int tn = dir ? (TT - 2 - t) : (t + 1);
      const ushort_t* gp = gxd + (size_t)tn * 8 * 6400;
#pragma unroll
      for (int i = 0; i < 4; i++) pf[i] = *(const short4_t*)(gp + loff[i]);
    }

    // B fragments: h, B[n=batch lm][k=quad*8+j]
    short8 bfr[4];
#pragma unroll
    for (int kt = 0; kt < 4; kt++)
      bfr[kt] = *(const short8*)(&hbuf[pb][lm][kt * 32 + quad * 8]);

#pragma unroll
    for (int i = 0; i < 4; i++) {
      if (i == 3 && w != 0) continue;      // wave-uniform
#pragma unroll
      for (int kt = 0; kt < 4; kt++)
        acc[i] = __builtin_amdgcn_mfma_f32_16x16x32_bf16(afragW[i][kt], bfr[kt], acc[i], 0, 0, 0);
    }

    // epilogue: gates are acc[i][0..3] directly; 7 transcendentals per item
#pragma unroll
    for (int i = 0; i < 4; i++) {
      if (i == 3 && w != 0) continue;
      float gi = acc[i][0], gf = acc[i][1], gg = acc[i][2], go = acc[i][3];
      float a  = 1.0f + fexp2(-K1 * gi);   // 1/sigm(gi)
      float b  = 1.0f + fexp2( K2 * gg);   // tanh(gg) = (b-2)/b
      float af = 1.0f + fexp2(-K1 * gf);   // 1/sigm(gf)
      float ab = a * b;
      float num = cst[i] * ab + (b - 2.0f) * af;
      float cn  = num * frcp(af * ab);
      cst[i] = cn;
      float c_ = 1.0f + fexp2(-K1 * go);   // 1/sigm(go)
      float cnc = fminf(cn, 30.0f);        // tanh(30)==1 in fp32; avoids inf/inf
      float d_ = 1.0f + fexp2( K2 * cnc);  // tanh(cn) = (d-2)/d
      float h  = (d_ - 2.0f) * frcp(c_ * d_);
      int j = nts[i] * 4 + quad;           // unit index
      hbuf[pb ^ 1][lm][j] = f2bf(h);
      size_t oidx = ((size_t)tt * BB + b0 + lm) * ostride + ocol + j;
      if (F32OUT) ((float*)outp)[oidx] = h;
      else        ((ushort_t*)outp)[oidx] = f2bf(h);
    }
    __syncthreads();
  }
}

// ---------------- launch ----------------
extern "C" void kernel_launch(void* const* d_in, const int* in_sizes, int n_in,
                              void* d_out, int out_size, void* d_ws, size_t ws_size,
                              hipStream_t stream) {
  const void* x_raw    = d_in[0];
  const void* wih0_raw = d_in[1];
  const void* whh0_raw = d_in[2];
  const void* b0_raw   = d_in[3];
  const void* wih1_raw = d_in[4];
  const void* whh1_raw = d_in[5];
  const void* b1_raw   = d_in[6];

  char* ws = (char*)d_ws;
  int*      FLAG = (int*)(ws + WS_FLAG);
  ushort_t* xT   = (ushort_t*)(ws + WS_XT);
  ushort_t* out0 = (ushort_t*)(ws + WS_OUT0);
  ushort_t* gx   = (ushort_t*)(ws + WS_GX);
  ushort_t* WIH0 = (ushort_t*)(ws + WS_WIH0);
  ushort_t* WHH  = (ushort_t*)(ws + WS_WHH);
  ushort_t* WIH1 = (ushort_t*)(ws + WS_WIH1);
  float*    BIAS = (float*)(ws + WS_BIAS);

  // 1) detect input dtype (data-dependent only -> graph-safe)
  detect_dtype<<<1, 256, 0, stream>>>((const ushort_t*)x_raw, FLAG);

  // 2) prep (flag-based inline conversion, no separate cvt passes)
  prep_weights<<<256, 256, 0, stream>>>(wih0_raw, whh0_raw, b0_raw,
                                        wih1_raw, whh1_raw, b1_raw,
                                        WIH0, WHH, WIH1, BIAS, FLAG);
  pack_x<<<dim3(128, 16), 256, 0, stream>>>(x_raw, xT, FLAG);
  zero_out0_pads<<<16384, 256, 0, stream>>>((unsigned*)out0);

  // layer 0 (bf16 internal output)
  gemm_gx<128><<<4096, 256, 0, stream>>>(xT, WIH0, BIAS, gx);
  lstm_layer<false><<<16, 512, 0, stream>>>(gx, WHH, out0, 256, 128);
  // layer 1 (fp32 output to d_out)
  gemm_gx<256><<<4096, 256, 0, stream>>>(out0, WIH1, BIAS + 2 * NG, gx);
  lstm_layer<true><<<16, 512, 0, stream>>>(gx, WHH + (size_t)2 * NG * 128, d_out, 200, 100);
}